// Round 1
// baseline (116.049 us; speedup 1.0000x reference)
//
#include <hip/hip_runtime.h>

// Varifold loss kxx + kyy - 2*kxy via mfma_f32_32x32x16_bf16.
// R11: two-phase (encode + fused main/reduce), no LDS staging.
//
// Phase 1 (vf_encode): encode every point once into bf16 MFMA fragments in
//   d_ws (A-form and B-form, S and D matrices), hi/lo-split (~fp24), with
//   -log2(e) folded into S so accS IS the exp2 argument. Also zeroes the
//   completion counter used by the fused reduction.
// Phase 2 (vf_main): trans-issue-bound MFMA+exp2 loop.
//   R11 change: B fragments are read DIRECTLY from global (L2-resident, 4MB
//   working set; each chunk re-read ~32x -> ~2.8 TB/s L2, far under 34.5)
//   with depth-1 software prefetch. This deletes the LDS staging loop
//   (~130 issue-cyc/wave) and BOTH __syncthreads/vmcnt(0) drains that
//   limited issue efficiency to 74%. Reduction fused via device-scope
//   counter: each block plain-stores its partial, __threadfence (release),
//   atomicAdd on counter; last block fences (acquire) and double-sums all
//   partials in fixed index order (bitwise-deterministic result).
//   xx/yy on upper-triangle 512x512 supertiles, off-diag weight 2.
//   No same-address float atomics (R5: serialized ~10ns each).
//
// Failed levers (do not retry): packed-f32 epilogue (R8, ~0), 8 blocks/CU
// occupancy (R8, ~0), VGPR cap below 128 (R9, -1.5us), SW pipeline depth 1
// on MFMA (R10, +2us), inline-asm MFMA (R7, corrupt).

typedef short bf16x8 __attribute__((ext_vector_type(8)));
typedef float f32x16 __attribute__((ext_vector_type(16)));
typedef float f32x2  __attribute__((ext_vector_type(2)));

#define NPTS 4096
#define BATCH 4
#define IBLK 128                   // 4 waves x one 32-row i-tile each
#define JCHUNK 512                 // 16 j-tiles of 32
#define LOG2E 1.4426950408889634f

#define NXY  (BATCH * 32 * 8)      // 1024 xy blocks (32 ib x 8 jc)
#define NSYM (BATCH * 36 * 4)      // 576 blocks per symmetric term
#define GRID_MAIN (NXY + 2 * NSYM) // 2176

// region stride: 4096 rows x 16 shorts
#define RSTRIDE 65536
// side: 0=xyz1/nor1 1=xyz2/nor2; form: 0=A 1=B; mat: 0=S 1=D
#define REG(side, form, mat, b) \
    (((((((side)*2 + (form))*2 + (mat))*BATCH) + (b))) * (size_t)RSTRIDE)
#define PARTIALS_OFF (32 * (size_t)RSTRIDE)   // shorts; = 4MB byte offset
#define COUNTER_OFF  (PARTIALS_OFF + 8192)    // shorts; = 4MB + 16KB

// upper-triangle 8x8 supertile table: entry = (g<<4)|j5, g<=j5
__constant__ unsigned char SU_TBL[36] = {
    0x00,0x01,0x02,0x03,0x04,0x05,0x06,0x07,
    0x11,0x12,0x13,0x14,0x15,0x16,0x17,
    0x22,0x23,0x24,0x25,0x26,0x27,
    0x33,0x34,0x35,0x36,0x37,
    0x44,0x45,0x46,0x47,
    0x55,0x56,0x57,
    0x66,0x67,
    0x77
};

static __device__ __forceinline__ short f2bf(float f) {
    unsigned u = __builtin_bit_cast(unsigned, f);
    unsigned r = u + 0x7fffu + ((u >> 16) & 1u);   // RNE
    return (short)(r >> 16);
}
// v -> h (exact bf16 value) + l (residual)
static __device__ __forceinline__ void split(float v, float& h, float& l) {
    unsigned u = __builtin_bit_cast(unsigned, v);
    unsigned rb = (u + 0x7fffu + ((u >> 16) & 1u)) & 0xffff0000u;
    h = __builtin_bit_cast(float, rb);
    l = v - h;
}

// slot pairing (A,B): (gh,1)(gl,1)(1,g'h)(1,g'l), per dim (uh,vh)(uh,vl)(ul,vh)
// u = 2*log2e*xi, v = xj, g = -log2e*|x|^2  => accS = -log2e * S_ij
static __device__ __forceinline__ void encodeA(float x0, float x1, float x2,
                                               float n0, float n1, float n2,
                                               float fS[16], float fD[16]) {
    float s2 = fmaf(x2, x2, fmaf(x1, x1, x0 * x0));
    float gh, gl; split(-LOG2E * s2, gh, gl);
    float u0h,u0l,u1h,u1l,u2h,u2l;
    split(2.f*LOG2E*x0, u0h, u0l);
    split(2.f*LOG2E*x1, u1h, u1l);
    split(2.f*LOG2E*x2, u2h, u2l);
    fS[0]=gh;  fS[1]=gl;  fS[2]=1.f; fS[3]=1.f;
    fS[4]=u0h; fS[5]=u0h; fS[6]=u0l;
    fS[7]=u1h; fS[8]=u1h; fS[9]=u1l;
    fS[10]=u2h; fS[11]=u2h; fS[12]=u2l;
    fS[13]=0.f; fS[14]=0.f; fS[15]=0.f;
    float m0h,m0l,m1h,m1l,m2h,m2l;
    split(n0, m0h, m0l); split(n1, m1h, m1l); split(n2, m2h, m2l);
    fD[0]=m0h; fD[1]=m0h; fD[2]=m0l;
    fD[3]=m1h; fD[4]=m1h; fD[5]=m1l;
    fD[6]=m2h; fD[7]=m2h; fD[8]=m2l;
#pragma unroll
    for (int k = 9; k < 16; ++k) fD[k] = 0.f;
}

static __device__ __forceinline__ void encodeB(float x0, float x1, float x2,
                                               float n0, float n1, float n2,
                                               float fS[16], float fD[16]) {
    float s2 = fmaf(x2, x2, fmaf(x1, x1, x0 * x0));
    float gh, gl; split(-LOG2E * s2, gh, gl);
    float v0h,v0l,v1h,v1l,v2h,v2l;
    split(x0, v0h, v0l); split(x1, v1h, v1l); split(x2, v2h, v2l);
    fS[0]=1.f; fS[1]=1.f; fS[2]=gh;  fS[3]=gl;
    fS[4]=v0h; fS[5]=v0l; fS[6]=v0h;
    fS[7]=v1h; fS[8]=v1l; fS[9]=v1h;
    fS[10]=v2h; fS[11]=v2l; fS[12]=v2h;
    fS[13]=0.f; fS[14]=0.f; fS[15]=0.f;
    float m0h,m0l,m1h,m1l,m2h,m2l;
    split(n0, m0h, m0l); split(n1, m1h, m1l); split(n2, m2h, m2l);
    fD[0]=m0h; fD[1]=m0l; fD[2]=m0h;
    fD[3]=m1h; fD[4]=m1l; fD[5]=m1h;
    fD[6]=m2h; fD[7]=m2l; fD[8]=m2h;
#pragma unroll
    for (int k = 9; k < 16; ++k) fD[k] = 0.f;
}

// write 16 floats as bf16 into two lane-major 16B units u0 (k0-7), u0+32 (k8-15)
static __device__ __forceinline__ void store_units(short* base, int u0, const float f[16]) {
    bf16x8 a, b;
#pragma unroll
    for (int k = 0; k < 8; ++k) { a[k] = f2bf(f[k]); b[k] = f2bf(f[k + 8]); }
    *(bf16x8*)&base[(size_t)u0 * 8] = a;
    *(bf16x8*)&base[((size_t)u0 + 32) * 8] = b;
}

__global__ __launch_bounds__(256)
void vf_encode(const float* __restrict__ xyz1, const float* __restrict__ xyz2,
               const float* __restrict__ nor1, const float* __restrict__ nor2,
               short* __restrict__ ws)
{
    int gid = blockIdx.x * 256 + threadIdx.x;   // 2*4*4096 = 32768 total
    int side = gid >> 14;
    int b    = (gid >> 12) & 3;
    int j    = gid & 4095;

    if (gid == 0) *(unsigned*)&ws[COUNTER_OFF] = 0u;   // re-arm fused reduce

    const float* px = side ? xyz2 : xyz1;
    const float* pn = side ? nor2 : nor1;
    size_t off = ((size_t)b * NPTS + j) * 3;
    float x0 = px[off], x1 = px[off+1], x2 = px[off+2];
    float n0 = pn[off], n1 = pn[off+1], n2 = pn[off+2];

    float fS[16], fD[16];
    int u0 = (j >> 5) * 64 + (j & 31);

    encodeA(x0, x1, x2, n0, n1, n2, fS, fD);
    store_units(ws + REG(side, 0, 0, b), u0, fS);
    store_units(ws + REG(side, 0, 1, b), u0, fD);
    encodeB(x0, x1, x2, n0, n1, n2, fS, fD);
    store_units(ws + REG(side, 1, 0, b), u0, fS);
    store_units(ws + REG(side, 1, 1, b), u0, fD);
}

// epilogue for one 32x32 tile: 16 exp2 (trans) + packed mul/fma (VOP3P)
static __device__ __forceinline__ void epi(const f32x16& aS, const f32x16& aD,
                                           f32x2& q0, f32x2& q1) {
#pragma unroll
    for (int e = 0; e < 16; e += 4) {
        f32x2 ex0, ex1, d0, d1;
        ex0[0] = __builtin_amdgcn_exp2f(aS[e+0]);
        ex0[1] = __builtin_amdgcn_exp2f(aS[e+1]);
        ex1[0] = __builtin_amdgcn_exp2f(aS[e+2]);
        ex1[1] = __builtin_amdgcn_exp2f(aS[e+3]);
        d0[0] = aD[e+0]; d0[1] = aD[e+1];
        d1[0] = aD[e+2]; d1[1] = aD[e+3];
        q0 = __builtin_elementwise_fma(ex0 * d0, d0, q0);   // v_pk_mul + v_pk_fma
        q1 = __builtin_elementwise_fma(ex1 * d1, d1, q1);
    }
}

__global__ __launch_bounds__(256, 4)   // 128 VGPR cap (R9: best)
void vf_main(short* __restrict__ ws, float* __restrict__ out)
{
    int blk = blockIdx.x;
    int term, b, ib, jc; float wgt;
    if (blk < NXY) {                         // xy: full grid
        term = 2; int r = blk;
        b = r & 3; r >>= 2;
        ib = r & 31; r >>= 5;
        jc = r;                              // 0..7
        wgt = -2.f;
    } else {                                 // xx / yy: upper-triangle supertiles
        int s = blk - NXY;
        term = (s < NSYM) ? 0 : 1;
        if (s >= NSYM) s -= NSYM;
        b = s & 3; s >>= 2;
        int sub = s & 3; s >>= 2;            // ib within 512-row supertile
        unsigned e = SU_TBL[s];
        int g = e >> 4, j5 = e & 15;
        ib = g * 4 + sub;
        jc = j5;                             // 0..7 (512-wide chunk)
        wgt = (g == j5) ? 1.f : 2.f;
    }

    int sideA = (term == 1) ? 1 : 0;
    int sideB = (term == 0) ? 0 : 1;

    const short* aSp = ws + REG(sideA, 0, 0, b);
    const short* aDp = ws + REG(sideA, 0, 1, b);
    const short* bSp = ws + REG(sideB, 1, 0, b) + (size_t)jc * 1024 * 8;
    const short* bDp = ws + REG(sideB, 1, 1, b) + (size_t)jc * 1024 * 8;

    const int tid  = threadIdx.x;
    const int lane = tid & 63;
    const int wv   = tid >> 6;

    // ---- A fragments: one 32-row i-tile per wave, lane-major 16B load ----
    int ua = (ib * 4 + wv) * 64 + lane;
    bf16x8 AS = *(const bf16x8*)&aSp[(size_t)ua * 8];
    bf16x8 AD = *(const bf16x8*)&aDp[(size_t)ua * 8];

    f32x16 z;
#pragma unroll
    for (int k = 0; k < 16; ++k) z[k] = 0.f;

    f32x2 q0 = {0.f, 0.f}, q1 = {0.f, 0.f};

    // ---- B fragments straight from global (L2-resident), prefetch depth 1 ----
    bf16x8 BS = *(const bf16x8*)&bSp[(size_t)lane * 8];
    bf16x8 BD = *(const bf16x8*)&bDp[(size_t)lane * 8];

#pragma unroll
    for (int jt = 0; jt < JCHUNK / 32; ++jt) {
        bf16x8 nBS = BS, nBD = BD;
        if (jt + 1 < JCHUNK / 32) {
            size_t u = ((size_t)(jt + 1) * 64 + lane) * 8;
            nBS = *(const bf16x8*)&bSp[u];
            nBD = *(const bf16x8*)&bDp[u];
        }
        f32x16 aSacc = __builtin_amdgcn_mfma_f32_32x32x16_bf16(AS, BS, z, 0, 0, 0);
        f32x16 aDacc = __builtin_amdgcn_mfma_f32_32x32x16_bf16(AD, BD, z, 0, 0, 0);
        epi(aSacc, aDacc, q0, q1);
        BS = nBS; BD = nBD;
    }

    float part = (q0[0] + q0[1]) + (q1[0] + q1[1]);
#pragma unroll
    for (int off = 32; off > 0; off >>= 1)
        part += __shfl_down(part, off, 64);

    __shared__ float red[4];
    __shared__ int lastflag;
    if (lane == 0) red[wv] = part;
    __syncthreads();
    if (tid == 0) {
        float s = (red[0] + red[1]) + (red[2] + red[3]);
        float* partials = (float*)&ws[PARTIALS_OFF];
        partials[blk] = wgt * s;               // plain store, distinct address
        __threadfence();                       // release: partial visible device-wide
        unsigned old = atomicAdd((unsigned*)&ws[COUNTER_OFF], 1u);
        lastflag = (old == GRID_MAIN - 1) ? 1 : 0;
    }
    __syncthreads();

    if (lastflag) {                            // exactly one block: fused reduce
        __threadfence();                       // acquire: invalidate stale L1/L2
        const float* partials = (const float*)&ws[PARTIALS_OFF];
        double s = 0.0;
#pragma unroll
        for (int k = 0; k < (GRID_MAIN + 255) / 256; ++k) {
            int idx = tid + k * 256;
            if (idx < GRID_MAIN) s += (double)partials[idx];
        }
#pragma unroll
        for (int off = 32; off > 0; off >>= 1)
            s += __shfl_down(s, off, 64);
        __shared__ double dred[4];
        if (lane == 0) dred[wv] = s;
        __syncthreads();
        if (tid == 0)
            out[0] = (float)((dred[0] + dred[1]) + (dred[2] + dred[3]));
    }
}

extern "C" void kernel_launch(void* const* d_in, const int* in_sizes, int n_in,
                              void* d_out, int out_size, void* d_ws, size_t ws_size,
                              hipStream_t stream) {
    const float* xyz1 = (const float*)d_in[0];
    const float* xyz2 = (const float*)d_in[1];
    const float* nor1 = (const float*)d_in[2];
    const float* nor2 = (const float*)d_in[3];
    float* out = (float*)d_out;
    short* ws  = (short*)d_ws;    // 4MB fragments + partials + counter

    vf_encode<<<(2 * BATCH * NPTS) / 256, 256, 0, stream>>>(xyz1, xyz2, nor1, nor2, ws);
    vf_main<<<GRID_MAIN, 256, 0, stream>>>(ws, out);
}